// Round 6
// baseline (245.232 us; speedup 1.0000x reference)
//
#include <hip/hip_runtime.h>
#include <float.h>

#define N_PTS   48
#define N_PAIRS 1128
#define C_TOT   2256
#define NE      46
#define DOC     277
#define DCOMB   286
#define GSTRIDE 288
#define DGRAPH  289
#define BATCH   4

typedef _Float16 h2 __attribute__((ext_vector_type(2)));

// ---------------- prep kernels ----------------

__global__ void center_kernel(const float* __restrict__ x, float* __restrict__ xc) {
    int row = blockIdx.x;              // 12 rows = b*3+d
    int t = threadIdx.x;               // 64 threads
    float v = (t < N_PTS) ? x[row * N_PTS + t] : 0.f;
    float s = v;
    #pragma unroll
    for (int m = 32; m >= 1; m >>= 1) s += __shfl_xor(s, m);
    if (t < N_PTS) xc[row * N_PTS + t] = v - s * (1.0f / N_PTS);
}

// LDS-tiled transpose: out[c*R + r] = in[r*C + c]
__global__ __launch_bounds__(256) void transpose_tiled(const float* __restrict__ in,
                                                       float* __restrict__ out, int R, int C) {
    __shared__ float tile[32][33];
    int r0 = blockIdx.x * 32, c0 = blockIdx.y * 32;
    int tx = threadIdx.x & 31, ty = threadIdx.x >> 5;   // 32 x 8
    #pragma unroll
    for (int yy = 0; yy < 4; yy++) {
        int r = r0 + ty + 8 * yy, c = c0 + tx;
        tile[ty + 8 * yy][tx] = (r < R && c < C) ? in[r * C + c] : 0.f;
    }
    __syncthreads();
    #pragma unroll
    for (int yy = 0; yy < 4; yy++) {
        int c = c0 + ty + 8 * yy, r = r0 + tx;
        if (c < C && r < R) out[(size_t)c * R + r] = tile[tx][ty + 8 * yy];
    }
}

// ---------------- stage 1: per-pair kernel (dual-c packed f16) ----------------

// Batcher odd-even mergesort on 64 slots pruned to NE=46, operating on
// h2 (two independent sorts in the two halves, v_pk_min/max_f16).
__device__ __forceinline__ void batcher46h2(h2 a[NE]) {
    #pragma unroll
    for (int p = 1; p < 64; p <<= 1) {
        #pragma unroll
        for (int k = p; k >= 1; k >>= 1) {
            #pragma unroll
            for (int j = k % p; j + k < 64; j += 2 * k) {
                #pragma unroll
                for (int i = 0; i < k; i++) {
                    int lo = i + j, hi = i + j + k;
                    if (hi < NE && (lo / (2 * p)) == (hi / (2 * p))) {
                        h2 mn = __builtin_elementwise_min(a[lo], a[hi]);
                        h2 mx = __builtin_elementwise_max(a[lo], a[hi]);
                        a[lo] = mn; a[hi] = mx;
                    }
                }
            }
        }
    }
}

__device__ __forceinline__ void decode_pair(int c, int& fi, int& se, int& pi, int& pj) {
    int cc = c % N_PAIRS;
    bool rev = c >= N_PAIRS;
    int i = 0, rem = cc;
    while (rem >= N_PTS - 1 - i) { rem -= N_PTS - 1 - i; i++; }
    int j = i + 1 + rem;
    pi = i; pj = j;
    fi = rev ? j : i; se = rev ? i : j;
}

__device__ __forceinline__ void pick_row(int k, float x0, float y0, float z0,
                                         float x1, float y1, float z1,
                                         float x2, float y2, float z2,
                                         float& u0, float& u1, float& u2) {
    u0 = (k == 0) ? x0 : (k == 1) ? x1 : x2;
    u1 = (k == 0) ? y0 : (k == 1) ? y1 : y2;
    u2 = (k == 0) ? z0 : (k == 1) ? z1 : z2;
}

__device__ __forceinline__ void sort2_dot(int e, const float* __restrict__ A_comb,
                                          const float* __restrict__ w_comb,
                                          const h2 (*MtVp)[NE],
                                          float* __restrict__ dst0,
                                          float* __restrict__ dst1) {
    float A0 = A_comb[e], A1 = A_comb[DOC + e], A2 = A_comb[2 * DOC + e];
    h2 A0p = { (_Float16)A0, (_Float16)A0 };
    h2 A1p = { (_Float16)A1, (_Float16)A1 };
    h2 A2p = { (_Float16)A2, (_Float16)A2 };
    h2 p[NE];
    #pragma unroll
    for (int n = 0; n < NE; n++)
        p[n] = A0p * MtVp[0][n] + A1p * MtVp[1][n] + A2p * MtVp[2][n];
    batcher46h2(p);
    float acc0 = 0.f, acc1 = 0.f;
    #pragma unroll
    for (int n = 0; n < NE; n++) {
        float w = w_comb[n * DOC + e];
        acc0 += (float)p[n].x * w;
        acc1 += (float)p[n].y * w;
    }
    dst0[9 + e] = acc0;
    dst1[9 + e] = acc1;
}

// 256 threads per block; block handles c0=2k, c1=2k+1 packed in h2 halves.
__global__ __launch_bounds__(256, 4) void pair_kernel(
        const float* __restrict__ xc, const float* __restrict__ A_comb,
        const float* __restrict__ w_comb, float* __restrict__ gvR) {
    int blk = blockIdx.x;
    int b = blk / N_PAIRS, k = blk % N_PAIRS;
    int c0 = 2 * k, c1 = 2 * k + 1;
    int tid = threadIdx.x;

    __shared__ float Xs[3][N_PTS];
    __shared__ float MtVf[2][3][NE];
    __shared__ h2 MtVp[3][NE];

    if (tid < 3 * N_PTS) ((float*)Xs)[tid] = xc[b * 3 * N_PTS + tid];
    __syncthreads();

    int f0, s0, i0, j0; decode_pair(c0, f0, s0, i0, j0);
    int f1, s1, i1, j1; decode_pair(c1, f1, s1, i1, j1);

    // both pairs' M rows in registers (uniform across block)
    float ax0 = Xs[0][f0], ay0 = Xs[1][f0], az0 = Xs[2][f0];
    float bx0 = Xs[0][s0], by0 = Xs[1][s0], bz0 = Xs[2][s0];
    float cx0 = ay0 * bz0 - az0 * by0;
    float cy0 = az0 * bx0 - ax0 * bz0;
    float cz0 = ax0 * by0 - ay0 * bx0;

    float ax1 = Xs[0][f1], ay1 = Xs[1][f1], az1 = Xs[2][f1];
    float bx1 = Xs[0][s1], by1 = Xs[1][s1], bz1 = Xs[2][s1];
    float cx1 = ay1 * bz1 - az1 * by1;
    float cy1 = az1 * bx1 - ax1 * bz1;
    float cz1 = ax1 * by1 - ay1 * bx1;

    float* dst0 = gvR + ((size_t)b * C_TOT + c0) * GSTRIDE;
    float* dst1 = gvR + ((size_t)b * C_TOT + c1) * GSTRIDE;

    // MtV (f32) for each c, by separate thread groups
    if (tid < NE) {
        int m = tid;
        int a = (m < i0) ? m : m + 1;
        a = (a < j0) ? a : a + 1;
        float v0 = Xs[0][a], v1 = Xs[1][a], v2 = Xs[2][a];
        MtVf[0][0][m] = ax0 * v0 + ay0 * v1 + az0 * v2;
        MtVf[0][1][m] = bx0 * v0 + by0 * v1 + bz0 * v2;
        MtVf[0][2][m] = cx0 * v0 + cy0 * v1 + cz0 * v2;
    } else if (tid >= 64 && tid < 64 + NE) {
        int m = tid - 64;
        int a = (m < i1) ? m : m + 1;
        a = (a < j1) ? a : a + 1;
        float v0 = Xs[0][a], v1 = Xs[1][a], v2 = Xs[2][a];
        MtVf[1][0][m] = ax1 * v0 + ay1 * v1 + az1 * v2;
        MtVf[1][1][m] = bx1 * v0 + by1 * v1 + bz1 * v2;
        MtVf[1][2][m] = cx1 * v0 + cy1 * v1 + cz1 * v2;
    }

    // MtM direct stores (exact f32), using register-only data
    if (tid >= 160 && tid < 169) {
        int q = tid - 160, kk = q / 3, ll = q % 3;
        float u0, u1, u2, v0, v1, v2;
        pick_row(kk, ax0, ay0, az0, bx0, by0, bz0, cx0, cy0, cz0, u0, u1, u2);
        pick_row(ll, ax0, ay0, az0, bx0, by0, bz0, cx0, cy0, cz0, v0, v1, v2);
        dst0[q] = u0 * v0 + u1 * v1 + u2 * v2;
    }
    if (tid >= 192 && tid < 201) {
        int q = tid - 192, kk = q / 3, ll = q % 3;
        float u0, u1, u2, v0, v1, v2;
        pick_row(kk, ax1, ay1, az1, bx1, by1, bz1, cx1, cy1, cz1, u0, u1, u2);
        pick_row(ll, ax1, ay1, az1, bx1, by1, bz1, cx1, cy1, cz1, v0, v1, v2);
        dst1[q] = u0 * v0 + u1 * v1 + u2 * v2;
    }
    if (tid == 224) { dst0[DCOMB] = 0.f; dst0[DCOMB + 1] = 0.f; }
    if (tid == 225) { dst1[DCOMB] = 0.f; dst1[DCOMB + 1] = 0.f; }
    __syncthreads();

    // pack MtV pairs into h2
    if (tid < 3 * NE) {
        int d = tid / NE, n = tid % NE;
        h2 t; t.x = (_Float16)MtVf[0][d][n]; t.y = (_Float16)MtVf[1][d][n];
        MtVp[d][n] = t;
    }
    __syncthreads();

    // e = tid (256 < 277 always valid)
    sort2_dot(tid, A_comb, w_comb, MtVp, dst0, dst1);
    // tail e = 256..276
    if (tid < DOC - 256)
        sort2_dot(256 + tid, A_comb, w_comb, MtVp, dst0, dst1);
}

// ---------------- stage 2a: projection GEMM ----------------
// P[b][e][c] = sum_d A_graph[d][e] * gvR[b][c][d]
#define KT 32

__global__ __launch_bounds__(256) void proj_gemm(
        const float* __restrict__ gvR, const float* __restrict__ A_graph,
        float* __restrict__ P) {
    __shared__ __align__(16) float As[KT][64];
    __shared__ __align__(16) float Gs[KT][68];
    int b = blockIdx.z;
    int e0 = blockIdx.y * 64;
    int c0 = blockIdx.x * 64;
    int tid = threadIdx.x;
    int tx = tid & 15, ty = tid >> 4;
    float acc[4][4] = {};
    const float* gbase = gvR + (size_t)b * C_TOT * GSTRIDE;

    for (int k0 = 0; k0 < GSTRIDE; k0 += KT) {
        #pragma unroll
        for (int o = 0; o < 8; o++) {
            int idx = o * 256 + tid;
            int kk = idx >> 6, ee = idx & 63;
            int k = k0 + kk, E = e0 + ee;
            As[kk][ee] = (k < DCOMB && E < DGRAPH) ? A_graph[k * DGRAPH + E] : 0.f;
        }
        int kk = tid & 31;
        int cb = tid >> 5;   // 0..7
        #pragma unroll
        for (int o = 0; o < 8; o++) {
            int ccol = o * 8 + cb;
            int C = c0 + ccol;
            Gs[kk][ccol] = (C < C_TOT) ? gbase[(size_t)C * GSTRIDE + k0 + kk] : 0.f;
        }
        __syncthreads();
        #pragma unroll
        for (int k = 0; k < KT; k++) {
            float4 av = *(const float4*)&As[k][ty * 4];
            float4 gq = *(const float4*)&Gs[k][tx * 4];
            float ar[4] = {av.x, av.y, av.z, av.w};
            float gr[4] = {gq.x, gq.y, gq.z, gq.w};
            #pragma unroll
            for (int ii = 0; ii < 4; ii++)
                #pragma unroll
                for (int jj = 0; jj < 4; jj++)
                    acc[ii][jj] += ar[ii] * gr[jj];
        }
        __syncthreads();
    }
    #pragma unroll
    for (int ii = 0; ii < 4; ii++) {
        int e = e0 + ty * 4 + ii;
        int c = c0 + tx * 4;
        if (e < DGRAPH && c < C_TOT) {
            float4 val = make_float4(acc[ii][0], acc[ii][1], acc[ii][2], acc[ii][3]);
            *(float4*)&P[((size_t)b * DGRAPH + e) * C_TOT + c] = val;
        }
    }
}

// ---------------- stage 2b: 4-wave in-register bitonic sort + dot ----------------

#define RPT 16
#define LSTRIDE 17

template<int J, int K>
__device__ __forceinline__ void bpass_in(float v[RPT], int tid) {
    bool upt = ((tid & (K >> 4)) == 0);          // valid for K>=16
    #pragma unroll
    for (int r = 0; r < RPT; r++) {
        int l = r ^ J;
        if (l > r) {
            bool up = (K < 16) ? ((r & K) == 0) : upt;
            float a = v[r], b = v[l];
            float mn = fminf(a, b), mx = fmaxf(a, b);
            v[r] = up ? mn : mx;
            v[l] = up ? mx : mn;
        }
    }
}

template<int JL, int K>
__device__ __forceinline__ void bpass_shfl(float v[RPT], int tid) {
    bool lower = (tid & JL) == 0;
    bool up = (tid & (K >> 4)) == 0;
    bool keep_min = (lower == up);
    #pragma unroll
    for (int r = 0; r < RPT; r++) {
        float pv = __shfl_xor(v[r], JL);
        float mn = fminf(v[r], pv), mx = fmaxf(v[r], pv);
        v[r] = keep_min ? mn : mx;
    }
}

template<int JL, int K>
__device__ __forceinline__ void bpass_lds(float v[RPT], int tid, float* lds) {
    __syncthreads();
    #pragma unroll
    for (int r = 0; r < RPT; r++) lds[tid * LSTRIDE + r] = v[r];
    __syncthreads();
    bool lower = (tid & JL) == 0;
    bool up = (tid & (K >> 4)) == 0;
    bool keep_min = (lower == up);
    int pbase = (tid ^ JL) * LSTRIDE;
    #pragma unroll
    for (int r = 0; r < RPT; r++) {
        float pv = lds[pbase + r];
        float mn = fminf(v[r], pv), mx = fmaxf(v[r], pv);
        v[r] = keep_min ? mn : mx;
    }
}

#define BIN4(K) bpass_in<8,K>(v,tid); bpass_in<4,K>(v,tid); \
                bpass_in<2,K>(v,tid); bpass_in<1,K>(v,tid)

__global__ __launch_bounds__(256) void sort_kernel(
        const float* __restrict__ P, const float* __restrict__ wgT,
        float* __restrict__ out) {
    int blk = blockIdx.x;
    int b = blk / DGRAPH, e = blk % DGRAPH;
    int tid = threadIdx.x;
    __shared__ float lds[256 * LSTRIDE];
    __shared__ float red[4];

    float v[RPT];
    const float* row = P + ((size_t)b * DGRAPH + e) * C_TOT;
    if (tid < 141) {
        const float4* r4 = (const float4*)(row + tid * RPT);
        #pragma unroll
        for (int q = 0; q < 4; q++) {
            float4 tq = r4[q];
            v[q * 4 + 0] = tq.x; v[q * 4 + 1] = tq.y;
            v[q * 4 + 2] = tq.z; v[q * 4 + 3] = tq.w;
        }
    } else {
        #pragma unroll
        for (int r = 0; r < RPT; r++) v[r] = FLT_MAX;
    }

    bpass_in<1,2>(v,tid);
    bpass_in<2,4>(v,tid); bpass_in<1,4>(v,tid);
    bpass_in<4,8>(v,tid); bpass_in<2,8>(v,tid); bpass_in<1,8>(v,tid);
    bpass_in<8,16>(v,tid); bpass_in<4,16>(v,tid); bpass_in<2,16>(v,tid); bpass_in<1,16>(v,tid);
    bpass_shfl<1,32>(v,tid);  BIN4(32);
    bpass_shfl<2,64>(v,tid);  bpass_shfl<1,64>(v,tid);  BIN4(64);
    bpass_shfl<4,128>(v,tid); bpass_shfl<2,128>(v,tid); bpass_shfl<1,128>(v,tid); BIN4(128);
    bpass_shfl<8,256>(v,tid); bpass_shfl<4,256>(v,tid); bpass_shfl<2,256>(v,tid); bpass_shfl<1,256>(v,tid); BIN4(256);
    bpass_shfl<16,512>(v,tid); bpass_shfl<8,512>(v,tid); bpass_shfl<4,512>(v,tid); bpass_shfl<2,512>(v,tid); bpass_shfl<1,512>(v,tid); BIN4(512);
    bpass_shfl<32,1024>(v,tid); bpass_shfl<16,1024>(v,tid); bpass_shfl<8,1024>(v,tid); bpass_shfl<4,1024>(v,tid); bpass_shfl<2,1024>(v,tid); bpass_shfl<1,1024>(v,tid); BIN4(1024);
    bpass_lds<64,2048>(v,tid,lds);
    bpass_shfl<32,2048>(v,tid); bpass_shfl<16,2048>(v,tid); bpass_shfl<8,2048>(v,tid); bpass_shfl<4,2048>(v,tid); bpass_shfl<2,2048>(v,tid); bpass_shfl<1,2048>(v,tid); BIN4(2048);
    bpass_lds<128,4096>(v,tid,lds);
    bpass_lds<64,4096>(v,tid,lds);
    bpass_shfl<32,4096>(v,tid); bpass_shfl<16,4096>(v,tid); bpass_shfl<8,4096>(v,tid); bpass_shfl<4,4096>(v,tid); bpass_shfl<2,4096>(v,tid); bpass_shfl<1,4096>(v,tid); BIN4(4096);

    float acc = 0.f;
    if (tid < 141) {
        const float4* w4 = (const float4*)(wgT + (size_t)e * C_TOT + tid * RPT);
        #pragma unroll
        for (int q = 0; q < 4; q++) {
            float4 tq = w4[q];
            acc += v[q * 4 + 0] * tq.x + v[q * 4 + 1] * tq.y
                 + v[q * 4 + 2] * tq.z + v[q * 4 + 3] * tq.w;
        }
    }
    #pragma unroll
    for (int m = 32; m >= 1; m >>= 1) acc += __shfl_xor(acc, m);
    int wave = tid >> 6, lane = tid & 63;
    if (lane == 0) red[wave] = acc;
    __syncthreads();
    if (tid == 0) out[b * DGRAPH + e] = red[0] + red[1] + red[2] + red[3];
}

// ---------------- launch ----------------

extern "C" void kernel_launch(void* const* d_in, const int* in_sizes, int n_in,
                              void* d_out, int out_size, void* d_ws, size_t ws_size,
                              hipStream_t stream) {
    const float* x       = (const float*)d_in[0];
    const float* A_comb  = (const float*)d_in[1];
    const float* w_comb  = (const float*)d_in[2];
    const float* A_graph = (const float*)d_in[3];
    const float* w_graph = (const float*)d_in[4];
    float* out = (float*)d_out;

    float* ws  = (float*)d_ws;
    float* xc  = ws;                          // 576
    float* wgT = xc + 576;                    // 289*2256 = 651,984
    float* gvR = wgT + 651984;                // 4*2256*288 = 2,598,912
    float* P   = gvR + 2598912;               // 4*289*2256 = 2,607,936

    center_kernel<<<12, 64, 0, stream>>>(x, xc);
    transpose_tiled<<<dim3((C_TOT + 31) / 32, (DGRAPH + 31) / 32), 256, 0, stream>>>(
        w_graph, wgT, C_TOT, DGRAPH);
    pair_kernel<<<BATCH * N_PAIRS, 256, 0, stream>>>(xc, A_comb, w_comb, gvR);
    proj_gemm<<<dim3(36, 5, BATCH), 256, 0, stream>>>(gvR, A_graph, P);
    sort_kernel<<<BATCH * DGRAPH, 256, 0, stream>>>(P, wgT, out);
}

// Round 7
// 171.271 us; speedup vs baseline: 1.4318x; 1.4318x over previous
//
#include <hip/hip_runtime.h>
#include <float.h>

#define N_PTS   48
#define N_PAIRS 1128
#define C_TOT   2256
#define NE      46
#define DOC     277
#define DCOMB   286
#define GSTRIDE 288
#define DGRAPH  289
#define BATCH   4

typedef _Float16 h2 __attribute__((ext_vector_type(2)));

// ---------------- prep kernels ----------------

__global__ void center_kernel(const float* __restrict__ x, float* __restrict__ xc) {
    int row = blockIdx.x;              // 12 rows = b*3+d
    int t = threadIdx.x;               // 64 threads
    float v = (t < N_PTS) ? x[row * N_PTS + t] : 0.f;
    float s = v;
    #pragma unroll
    for (int m = 32; m >= 1; m >>= 1) s += __shfl_xor(s, m);
    if (t < N_PTS) xc[row * N_PTS + t] = v - s * (1.0f / N_PTS);
}

// LDS-tiled transpose: out[c*R + r] = in[r*C + c]
__global__ __launch_bounds__(256) void transpose_tiled(const float* __restrict__ in,
                                                       float* __restrict__ out, int R, int C) {
    __shared__ float tile[32][33];
    int r0 = blockIdx.x * 32, c0 = blockIdx.y * 32;
    int tx = threadIdx.x & 31, ty = threadIdx.x >> 5;   // 32 x 8
    #pragma unroll
    for (int yy = 0; yy < 4; yy++) {
        int r = r0 + ty + 8 * yy, c = c0 + tx;
        tile[ty + 8 * yy][tx] = (r < R && c < C) ? in[r * C + c] : 0.f;
    }
    __syncthreads();
    #pragma unroll
    for (int yy = 0; yy < 4; yy++) {
        int c = c0 + ty + 8 * yy, r = r0 + tx;
        if (c < C && r < R) out[(size_t)c * R + r] = tile[tx][ty + 8 * yy];
    }
}

// ---------------- stage 1: per-pair kernel (dual-c packed f16) ----------------

// Batcher odd-even mergesort on 64 slots pruned to NE=46, operating on
// h2 (two independent sorts in the two halves, v_pk_min/max_f16).
__device__ __forceinline__ void batcher46h2(h2 a[NE]) {
    #pragma unroll
    for (int p = 1; p < 64; p <<= 1) {
        #pragma unroll
        for (int k = p; k >= 1; k >>= 1) {
            #pragma unroll
            for (int j = k % p; j + k < 64; j += 2 * k) {
                #pragma unroll
                for (int i = 0; i < k; i++) {
                    int lo = i + j, hi = i + j + k;
                    if (hi < NE && (lo / (2 * p)) == (hi / (2 * p))) {
                        h2 mn = __builtin_elementwise_min(a[lo], a[hi]);
                        h2 mx = __builtin_elementwise_max(a[lo], a[hi]);
                        a[lo] = mn; a[hi] = mx;
                    }
                }
            }
        }
    }
}

__device__ __forceinline__ void decode_pair(int c, int& fi, int& se, int& pi, int& pj) {
    int cc = c % N_PAIRS;
    bool rev = c >= N_PAIRS;
    int i = 0, rem = cc;
    while (rem >= N_PTS - 1 - i) { rem -= N_PTS - 1 - i; i++; }
    int j = i + 1 + rem;
    pi = i; pj = j;
    fi = rev ? j : i; se = rev ? i : j;
}

__device__ __forceinline__ void pick_row(int k, float x0, float y0, float z0,
                                         float x1, float y1, float z1,
                                         float x2, float y2, float z2,
                                         float& u0, float& u1, float& u2) {
    u0 = (k == 0) ? x0 : (k == 1) ? x1 : x2;
    u1 = (k == 0) ? y0 : (k == 1) ? y1 : y2;
    u2 = (k == 0) ? z0 : (k == 1) ? z1 : z2;
}

__device__ __forceinline__ void sort2_dot(int e, const float* __restrict__ A_comb,
                                          const float* __restrict__ w_comb,
                                          const h2 (*MtVp)[NE],
                                          float* __restrict__ dst0,
                                          float* __restrict__ dst1) {
    float A0 = A_comb[e], A1 = A_comb[DOC + e], A2 = A_comb[2 * DOC + e];
    h2 A0p = { (_Float16)A0, (_Float16)A0 };
    h2 A1p = { (_Float16)A1, (_Float16)A1 };
    h2 A2p = { (_Float16)A2, (_Float16)A2 };
    h2 p[NE];
    #pragma unroll
    for (int n = 0; n < NE; n++)
        p[n] = A0p * MtVp[0][n] + A1p * MtVp[1][n] + A2p * MtVp[2][n];
    batcher46h2(p);
    float acc0 = 0.f, acc1 = 0.f;
    #pragma unroll
    for (int n = 0; n < NE; n++) {
        float w = w_comb[n * DOC + e];
        acc0 += (float)p[n].x * w;
        acc1 += (float)p[n].y * w;
    }
    dst0[9 + e] = acc0;
    dst1[9 + e] = acc1;
}

// 256 threads per block; block handles c0=2k, c1=2k+1 packed in h2 halves.
// NOTE: no min-waves clamp — the packed sort needs ~46 live VGPRs; a 64-VGPR
// cap (launch_bounds(256,4)) spilled the sort array to scratch (562MB writes).
__global__ __launch_bounds__(256) void pair_kernel(
        const float* __restrict__ xc, const float* __restrict__ A_comb,
        const float* __restrict__ w_comb, float* __restrict__ gvR) {
    int blk = blockIdx.x;
    int b = blk / N_PAIRS, k = blk % N_PAIRS;
    int c0 = 2 * k, c1 = 2 * k + 1;
    int tid = threadIdx.x;

    __shared__ float Xs[3][N_PTS];
    __shared__ float MtVf[2][3][NE];
    __shared__ h2 MtVp[3][NE];

    if (tid < 3 * N_PTS) ((float*)Xs)[tid] = xc[b * 3 * N_PTS + tid];
    __syncthreads();

    int f0, s0, i0, j0; decode_pair(c0, f0, s0, i0, j0);
    int f1, s1, i1, j1; decode_pair(c1, f1, s1, i1, j1);

    // both pairs' M rows in registers (uniform across block)
    float ax0 = Xs[0][f0], ay0 = Xs[1][f0], az0 = Xs[2][f0];
    float bx0 = Xs[0][s0], by0 = Xs[1][s0], bz0 = Xs[2][s0];
    float cx0 = ay0 * bz0 - az0 * by0;
    float cy0 = az0 * bx0 - ax0 * bz0;
    float cz0 = ax0 * by0 - ay0 * bx0;

    float ax1 = Xs[0][f1], ay1 = Xs[1][f1], az1 = Xs[2][f1];
    float bx1 = Xs[0][s1], by1 = Xs[1][s1], bz1 = Xs[2][s1];
    float cx1 = ay1 * bz1 - az1 * by1;
    float cy1 = az1 * bx1 - ax1 * bz1;
    float cz1 = ax1 * by1 - ay1 * bx1;

    float* dst0 = gvR + ((size_t)b * C_TOT + c0) * GSTRIDE;
    float* dst1 = gvR + ((size_t)b * C_TOT + c1) * GSTRIDE;

    // MtV (f32) for each c, by separate thread groups
    if (tid < NE) {
        int m = tid;
        int a = (m < i0) ? m : m + 1;
        a = (a < j0) ? a : a + 1;
        float v0 = Xs[0][a], v1 = Xs[1][a], v2 = Xs[2][a];
        MtVf[0][0][m] = ax0 * v0 + ay0 * v1 + az0 * v2;
        MtVf[0][1][m] = bx0 * v0 + by0 * v1 + bz0 * v2;
        MtVf[0][2][m] = cx0 * v0 + cy0 * v1 + cz0 * v2;
    } else if (tid >= 64 && tid < 64 + NE) {
        int m = tid - 64;
        int a = (m < i1) ? m : m + 1;
        a = (a < j1) ? a : a + 1;
        float v0 = Xs[0][a], v1 = Xs[1][a], v2 = Xs[2][a];
        MtVf[1][0][m] = ax1 * v0 + ay1 * v1 + az1 * v2;
        MtVf[1][1][m] = bx1 * v0 + by1 * v1 + bz1 * v2;
        MtVf[1][2][m] = cx1 * v0 + cy1 * v1 + cz1 * v2;
    }

    // MtM direct stores (exact f32), using register-only data
    if (tid >= 160 && tid < 169) {
        int q = tid - 160, kk = q / 3, ll = q % 3;
        float u0, u1, u2, v0, v1, v2;
        pick_row(kk, ax0, ay0, az0, bx0, by0, bz0, cx0, cy0, cz0, u0, u1, u2);
        pick_row(ll, ax0, ay0, az0, bx0, by0, bz0, cx0, cy0, cz0, v0, v1, v2);
        dst0[q] = u0 * v0 + u1 * v1 + u2 * v2;
    }
    if (tid >= 192 && tid < 201) {
        int q = tid - 192, kk = q / 3, ll = q % 3;
        float u0, u1, u2, v0, v1, v2;
        pick_row(kk, ax1, ay1, az1, bx1, by1, bz1, cx1, cy1, cz1, u0, u1, u2);
        pick_row(ll, ax1, ay1, az1, bx1, by1, bz1, cx1, cy1, cz1, v0, v1, v2);
        dst1[q] = u0 * v0 + u1 * v1 + u2 * v2;
    }
    if (tid == 224) { dst0[DCOMB] = 0.f; dst0[DCOMB + 1] = 0.f; }
    if (tid == 225) { dst1[DCOMB] = 0.f; dst1[DCOMB + 1] = 0.f; }
    __syncthreads();

    // pack MtV pairs into h2
    if (tid < 3 * NE) {
        int d = tid / NE, n = tid % NE;
        h2 t; t.x = (_Float16)MtVf[0][d][n]; t.y = (_Float16)MtVf[1][d][n];
        MtVp[d][n] = t;
    }
    __syncthreads();

    // e = tid (256 < 277 always valid)
    sort2_dot(tid, A_comb, w_comb, MtVp, dst0, dst1);
    // tail e = 256..276
    if (tid < DOC - 256)
        sort2_dot(256 + tid, A_comb, w_comb, MtVp, dst0, dst1);
}

// ---------------- stage 2a: projection GEMM ----------------
// P[b][e][c] = sum_d A_graph[d][e] * gvR[b][c][d]
#define KT 32

__global__ __launch_bounds__(256) void proj_gemm(
        const float* __restrict__ gvR, const float* __restrict__ A_graph,
        float* __restrict__ P) {
    __shared__ __align__(16) float As[KT][64];
    __shared__ __align__(16) float Gs[KT][68];
    int b = blockIdx.z;
    int e0 = blockIdx.y * 64;
    int c0 = blockIdx.x * 64;
    int tid = threadIdx.x;
    int tx = tid & 15, ty = tid >> 4;
    float acc[4][4] = {};
    const float* gbase = gvR + (size_t)b * C_TOT * GSTRIDE;

    for (int k0 = 0; k0 < GSTRIDE; k0 += KT) {
        #pragma unroll
        for (int o = 0; o < 8; o++) {
            int idx = o * 256 + tid;
            int kk = idx >> 6, ee = idx & 63;
            int k = k0 + kk, E = e0 + ee;
            As[kk][ee] = (k < DCOMB && E < DGRAPH) ? A_graph[k * DGRAPH + E] : 0.f;
        }
        int kk = tid & 31;
        int cb = tid >> 5;   // 0..7
        #pragma unroll
        for (int o = 0; o < 8; o++) {
            int ccol = o * 8 + cb;
            int C = c0 + ccol;
            Gs[kk][ccol] = (C < C_TOT) ? gbase[(size_t)C * GSTRIDE + k0 + kk] : 0.f;
        }
        __syncthreads();
        #pragma unroll
        for (int k = 0; k < KT; k++) {
            float4 av = *(const float4*)&As[k][ty * 4];
            float4 gq = *(const float4*)&Gs[k][tx * 4];
            float ar[4] = {av.x, av.y, av.z, av.w};
            float gr[4] = {gq.x, gq.y, gq.z, gq.w};
            #pragma unroll
            for (int ii = 0; ii < 4; ii++)
                #pragma unroll
                for (int jj = 0; jj < 4; jj++)
                    acc[ii][jj] += ar[ii] * gr[jj];
        }
        __syncthreads();
    }
    #pragma unroll
    for (int ii = 0; ii < 4; ii++) {
        int e = e0 + ty * 4 + ii;
        int c = c0 + tx * 4;
        if (e < DGRAPH && c < C_TOT) {
            float4 val = make_float4(acc[ii][0], acc[ii][1], acc[ii][2], acc[ii][3]);
            *(float4*)&P[((size_t)b * DGRAPH + e) * C_TOT + c] = val;
        }
    }
}

// ---------------- stage 2b: 4-wave in-register bitonic sort + dot ----------------

#define RPT 16
#define LSTRIDE 17

template<int J, int K>
__device__ __forceinline__ void bpass_in(float v[RPT], int tid) {
    bool upt = ((tid & (K >> 4)) == 0);          // valid for K>=16
    #pragma unroll
    for (int r = 0; r < RPT; r++) {
        int l = r ^ J;
        if (l > r) {
            bool up = (K < 16) ? ((r & K) == 0) : upt;
            float a = v[r], b = v[l];
            float mn = fminf(a, b), mx = fmaxf(a, b);
            v[r] = up ? mn : mx;
            v[l] = up ? mx : mn;
        }
    }
}

template<int JL, int K>
__device__ __forceinline__ void bpass_shfl(float v[RPT], int tid) {
    bool lower = (tid & JL) == 0;
    bool up = (tid & (K >> 4)) == 0;
    bool keep_min = (lower == up);
    #pragma unroll
    for (int r = 0; r < RPT; r++) {
        float pv = __shfl_xor(v[r], JL);
        float mn = fminf(v[r], pv), mx = fmaxf(v[r], pv);
        v[r] = keep_min ? mn : mx;
    }
}

template<int JL, int K>
__device__ __forceinline__ void bpass_lds(float v[RPT], int tid, float* lds) {
    __syncthreads();
    #pragma unroll
    for (int r = 0; r < RPT; r++) lds[tid * LSTRIDE + r] = v[r];
    __syncthreads();
    bool lower = (tid & JL) == 0;
    bool up = (tid & (K >> 4)) == 0;
    bool keep_min = (lower == up);
    int pbase = (tid ^ JL) * LSTRIDE;
    #pragma unroll
    for (int r = 0; r < RPT; r++) {
        float pv = lds[pbase + r];
        float mn = fminf(v[r], pv), mx = fmaxf(v[r], pv);
        v[r] = keep_min ? mn : mx;
    }
}

#define BIN4(K) bpass_in<8,K>(v,tid); bpass_in<4,K>(v,tid); \
                bpass_in<2,K>(v,tid); bpass_in<1,K>(v,tid)

__global__ __launch_bounds__(256) void sort_kernel(
        const float* __restrict__ P, const float* __restrict__ wgT,
        float* __restrict__ out) {
    int blk = blockIdx.x;
    int b = blk / DGRAPH, e = blk % DGRAPH;
    int tid = threadIdx.x;
    __shared__ float lds[256 * LSTRIDE];
    __shared__ float red[4];

    float v[RPT];
    const float* row = P + ((size_t)b * DGRAPH + e) * C_TOT;
    if (tid < 141) {
        const float4* r4 = (const float4*)(row + tid * RPT);
        #pragma unroll
        for (int q = 0; q < 4; q++) {
            float4 tq = r4[q];
            v[q * 4 + 0] = tq.x; v[q * 4 + 1] = tq.y;
            v[q * 4 + 2] = tq.z; v[q * 4 + 3] = tq.w;
        }
    } else {
        #pragma unroll
        for (int r = 0; r < RPT; r++) v[r] = FLT_MAX;
    }

    bpass_in<1,2>(v,tid);
    bpass_in<2,4>(v,tid); bpass_in<1,4>(v,tid);
    bpass_in<4,8>(v,tid); bpass_in<2,8>(v,tid); bpass_in<1,8>(v,tid);
    bpass_in<8,16>(v,tid); bpass_in<4,16>(v,tid); bpass_in<2,16>(v,tid); bpass_in<1,16>(v,tid);
    bpass_shfl<1,32>(v,tid);  BIN4(32);
    bpass_shfl<2,64>(v,tid);  bpass_shfl<1,64>(v,tid);  BIN4(64);
    bpass_shfl<4,128>(v,tid); bpass_shfl<2,128>(v,tid); bpass_shfl<1,128>(v,tid); BIN4(128);
    bpass_shfl<8,256>(v,tid); bpass_shfl<4,256>(v,tid); bpass_shfl<2,256>(v,tid); bpass_shfl<1,256>(v,tid); BIN4(256);
    bpass_shfl<16,512>(v,tid); bpass_shfl<8,512>(v,tid); bpass_shfl<4,512>(v,tid); bpass_shfl<2,512>(v,tid); bpass_shfl<1,512>(v,tid); BIN4(512);
    bpass_shfl<32,1024>(v,tid); bpass_shfl<16,1024>(v,tid); bpass_shfl<8,1024>(v,tid); bpass_shfl<4,1024>(v,tid); bpass_shfl<2,1024>(v,tid); bpass_shfl<1,1024>(v,tid); BIN4(1024);
    bpass_lds<64,2048>(v,tid,lds);
    bpass_shfl<32,2048>(v,tid); bpass_shfl<16,2048>(v,tid); bpass_shfl<8,2048>(v,tid); bpass_shfl<4,2048>(v,tid); bpass_shfl<2,2048>(v,tid); bpass_shfl<1,2048>(v,tid); BIN4(2048);
    bpass_lds<128,4096>(v,tid,lds);
    bpass_lds<64,4096>(v,tid,lds);
    bpass_shfl<32,4096>(v,tid); bpass_shfl<16,4096>(v,tid); bpass_shfl<8,4096>(v,tid); bpass_shfl<4,4096>(v,tid); bpass_shfl<2,4096>(v,tid); bpass_shfl<1,4096>(v,tid); BIN4(4096);

    float acc = 0.f;
    if (tid < 141) {
        const float4* w4 = (const float4*)(wgT + (size_t)e * C_TOT + tid * RPT);
        #pragma unroll
        for (int q = 0; q < 4; q++) {
            float4 tq = w4[q];
            acc += v[q * 4 + 0] * tq.x + v[q * 4 + 1] * tq.y
                 + v[q * 4 + 2] * tq.z + v[q * 4 + 3] * tq.w;
        }
    }
    #pragma unroll
    for (int m = 32; m >= 1; m >>= 1) acc += __shfl_xor(acc, m);
    int wave = tid >> 6, lane = tid & 63;
    if (lane == 0) red[wave] = acc;
    __syncthreads();
    if (tid == 0) out[b * DGRAPH + e] = red[0] + red[1] + red[2] + red[3];
}

// ---------------- launch ----------------

extern "C" void kernel_launch(void* const* d_in, const int* in_sizes, int n_in,
                              void* d_out, int out_size, void* d_ws, size_t ws_size,
                              hipStream_t stream) {
    const float* x       = (const float*)d_in[0];
    const float* A_comb  = (const float*)d_in[1];
    const float* w_comb  = (const float*)d_in[2];
    const float* A_graph = (const float*)d_in[3];
    const float* w_graph = (const float*)d_in[4];
    float* out = (float*)d_out;

    float* ws  = (float*)d_ws;
    float* xc  = ws;                          // 576
    float* wgT = xc + 576;                    // 289*2256 = 651,984
    float* gvR = wgT + 651984;                // 4*2256*288 = 2,598,912
    float* P   = gvR + 2598912;               // 4*289*2256 = 2,607,936

    center_kernel<<<12, 64, 0, stream>>>(x, xc);
    transpose_tiled<<<dim3((C_TOT + 31) / 32, (DGRAPH + 31) / 32), 256, 0, stream>>>(
        w_graph, wgT, C_TOT, DGRAPH);
    pair_kernel<<<BATCH * N_PAIRS, 256, 0, stream>>>(xc, A_comb, w_comb, gvR);
    proj_gemm<<<dim3(36, 5, BATCH), 256, 0, stream>>>(gvR, A_graph, P);
    sort_kernel<<<BATCH * DGRAPH, 256, 0, stream>>>(P, wgT, out);
}

// Round 8
// 153.829 us; speedup vs baseline: 1.5942x; 1.1134x over previous
//
#include <hip/hip_runtime.h>
#include <float.h>

#define N_PTS   48
#define N_PAIRS 1128
#define C_TOT   2256
#define NE      46
#define DOC     277
#define DCOMB   286
#define GSTRIDE 288
#define DGRAPH  289
#define BATCH   4

typedef _Float16 h2 __attribute__((ext_vector_type(2)));
typedef _Float16 h8 __attribute__((ext_vector_type(8)));

// ---------------- prep kernels ----------------

__global__ void center_kernel(const float* __restrict__ x, float* __restrict__ xc) {
    int row = blockIdx.x;              // 12 rows = b*3+d
    int t = threadIdx.x;               // 64 threads
    float v = (t < N_PTS) ? x[row * N_PTS + t] : 0.f;
    float s = v;
    #pragma unroll
    for (int m = 32; m >= 1; m >>= 1) s += __shfl_xor(s, m);
    if (t < N_PTS) xc[row * N_PTS + t] = v - s * (1.0f / N_PTS);
}

// LDS-tiled transpose: out[c*R + r] = in[r*C + c]
__global__ __launch_bounds__(256) void transpose_tiled(const float* __restrict__ in,
                                                       float* __restrict__ out, int R, int C) {
    __shared__ float tile[32][33];
    int r0 = blockIdx.x * 32, c0 = blockIdx.y * 32;
    int tx = threadIdx.x & 31, ty = threadIdx.x >> 5;   // 32 x 8
    #pragma unroll
    for (int yy = 0; yy < 4; yy++) {
        int r = r0 + ty + 8 * yy, c = c0 + tx;
        tile[ty + 8 * yy][tx] = (r < R && c < C) ? in[r * C + c] : 0.f;
    }
    __syncthreads();
    #pragma unroll
    for (int yy = 0; yy < 4; yy++) {
        int c = c0 + ty + 8 * yy, r = r0 + tx;
        if (c < C && r < R) out[(size_t)c * R + r] = tile[tx][ty + 8 * yy];
    }
}

// ---------------- stage 1: per-pair kernel (dual-c packed f16) ----------------

// Batcher odd-even mergesort on 64 slots pruned to NE=46, operating on
// h2 (two independent sorts in the two halves, v_pk_min/max_f16).
__device__ __forceinline__ void batcher46h2(h2 a[NE]) {
    #pragma unroll
    for (int p = 1; p < 64; p <<= 1) {
        #pragma unroll
        for (int k = p; k >= 1; k >>= 1) {
            #pragma unroll
            for (int j = k % p; j + k < 64; j += 2 * k) {
                #pragma unroll
                for (int i = 0; i < k; i++) {
                    int lo = i + j, hi = i + j + k;
                    if (hi < NE && (lo / (2 * p)) == (hi / (2 * p))) {
                        h2 mn = __builtin_elementwise_min(a[lo], a[hi]);
                        h2 mx = __builtin_elementwise_max(a[lo], a[hi]);
                        a[lo] = mn; a[hi] = mx;
                    }
                }
            }
        }
    }
}

__device__ __forceinline__ void decode_pair(int c, int& fi, int& se, int& pi, int& pj) {
    int cc = c % N_PAIRS;
    bool rev = c >= N_PAIRS;
    int i = 0, rem = cc;
    while (rem >= N_PTS - 1 - i) { rem -= N_PTS - 1 - i; i++; }
    int j = i + 1 + rem;
    pi = i; pj = j;
    fi = rev ? j : i; se = rev ? i : j;
}

__device__ __forceinline__ void pick_row(int k, float x0, float y0, float z0,
                                         float x1, float y1, float z1,
                                         float x2, float y2, float z2,
                                         float& u0, float& u1, float& u2) {
    u0 = (k == 0) ? x0 : (k == 1) ? x1 : x2;
    u1 = (k == 0) ? y0 : (k == 1) ? y1 : y2;
    u2 = (k == 0) ? z0 : (k == 1) ? z1 : z2;
}

// 320 threads per block (5 waves); block handles c0=2k, c1=2k+1 packed in h2
// halves. One packed sort per thread (e = tid < 277) -> single sort phase,
// single inline of the sort (keeps VGPR down; R7's dual inline hit 124 VGPR).
__global__ __launch_bounds__(320) void pair_kernel(
        const float* __restrict__ xc, const float* __restrict__ A_comb,
        const float* __restrict__ w_comb, float* __restrict__ gvR) {
    int blk = blockIdx.x;
    int b = blk / N_PAIRS, k = blk % N_PAIRS;
    int c0 = 2 * k, c1 = 2 * k + 1;
    int tid = threadIdx.x;

    __shared__ float Xs[3][N_PTS];
    __shared__ h8 MtVp8[3][12];             // rows padded to 48 h2 (96 halves)
    _Float16* MtVh = (_Float16*)MtVp8;      // row d at d*96; entry n at n*2 + half

    if (tid < 3 * N_PTS) ((float*)Xs)[tid] = xc[b * 3 * N_PTS + tid];
    __syncthreads();

    int f0, s0, i0, j0; decode_pair(c0, f0, s0, i0, j0);
    int f1, s1, i1, j1; decode_pair(c1, f1, s1, i1, j1);

    float ax0 = Xs[0][f0], ay0 = Xs[1][f0], az0 = Xs[2][f0];
    float bx0 = Xs[0][s0], by0 = Xs[1][s0], bz0 = Xs[2][s0];
    float cx0 = ay0 * bz0 - az0 * by0;
    float cy0 = az0 * bx0 - ax0 * bz0;
    float cz0 = ax0 * by0 - ay0 * bx0;

    float ax1 = Xs[0][f1], ay1 = Xs[1][f1], az1 = Xs[2][f1];
    float bx1 = Xs[0][s1], by1 = Xs[1][s1], bz1 = Xs[2][s1];
    float cx1 = ay1 * bz1 - az1 * by1;
    float cy1 = az1 * bx1 - ax1 * bz1;
    float cz1 = ax1 * by1 - ay1 * bx1;

    float* dst0 = gvR + ((size_t)b * C_TOT + c0) * GSTRIDE;
    float* dst1 = gvR + ((size_t)b * C_TOT + c1) * GSTRIDE;

    // MtV columns written directly as f16 halves (b16 stores, no staging array)
    if (tid < NE) {
        int m = tid;
        int a = (m < i0) ? m : m + 1;
        a = (a < j0) ? a : a + 1;
        float v0 = Xs[0][a], v1 = Xs[1][a], v2 = Xs[2][a];
        MtVh[0 * 96 + m * 2] = (_Float16)(ax0 * v0 + ay0 * v1 + az0 * v2);
        MtVh[1 * 96 + m * 2] = (_Float16)(bx0 * v0 + by0 * v1 + bz0 * v2);
        MtVh[2 * 96 + m * 2] = (_Float16)(cx0 * v0 + cy0 * v1 + cz0 * v2);
    } else if (tid >= 64 && tid < 64 + NE) {
        int m = tid - 64;
        int a = (m < i1) ? m : m + 1;
        a = (a < j1) ? a : a + 1;
        float v0 = Xs[0][a], v1 = Xs[1][a], v2 = Xs[2][a];
        MtVh[0 * 96 + m * 2 + 1] = (_Float16)(ax1 * v0 + ay1 * v1 + az1 * v2);
        MtVh[1 * 96 + m * 2 + 1] = (_Float16)(bx1 * v0 + by1 * v1 + bz1 * v2);
        MtVh[2 * 96 + m * 2 + 1] = (_Float16)(cx1 * v0 + cy1 * v1 + cz1 * v2);
    } else if (tid >= 128 && tid < 134) {
        int q = tid - 128;
        int d = q >> 1, n = 46 + (q & 1);   // pad entries n=46,47 of each row
        ((h2*)MtVp8)[d * 48 + n] = (h2){(_Float16)0.f, (_Float16)0.f};
    }

    // MtM direct stores (exact f32)
    if (tid >= 160 && tid < 169) {
        int q = tid - 160, kk = q / 3, ll = q % 3;
        float u0, u1, u2, v0, v1, v2;
        pick_row(kk, ax0, ay0, az0, bx0, by0, bz0, cx0, cy0, cz0, u0, u1, u2);
        pick_row(ll, ax0, ay0, az0, bx0, by0, bz0, cx0, cy0, cz0, v0, v1, v2);
        dst0[q] = u0 * v0 + u1 * v1 + u2 * v2;
    }
    if (tid >= 192 && tid < 201) {
        int q = tid - 192, kk = q / 3, ll = q % 3;
        float u0, u1, u2, v0, v1, v2;
        pick_row(kk, ax1, ay1, az1, bx1, by1, bz1, cx1, cy1, cz1, u0, u1, u2);
        pick_row(ll, ax1, ay1, az1, bx1, by1, bz1, cx1, cy1, cz1, v0, v1, v2);
        dst1[q] = u0 * v0 + u1 * v1 + u2 * v2;
    }
    if (tid == 224) { dst0[DCOMB] = 0.f; dst0[DCOMB + 1] = 0.f; }
    if (tid == 225) { dst1[DCOMB] = 0.f; dst1[DCOMB + 1] = 0.f; }
    __syncthreads();

    if (tid < DOC) {
        int e = tid;
        float A0 = A_comb[e], A1 = A_comb[DOC + e], A2 = A_comb[2 * DOC + e];
        h2 A0p = { (_Float16)A0, (_Float16)A0 };
        h2 A1p = { (_Float16)A1, (_Float16)A1 };
        h2 A2p = { (_Float16)A2, (_Float16)A2 };
        h2 p[NE];
        // vectorized LDS reads: 12 x 3 ds_read_b128 instead of 138 ds_read_b32
        #pragma unroll
        for (int c8 = 0; c8 < 12; c8++) {
            h8 m0 = MtVp8[0][c8];
            h8 m1 = MtVp8[1][c8];
            h8 m2 = MtVp8[2][c8];
            #pragma unroll
            for (int q = 0; q < 4; q++) {
                int n = c8 * 4 + q;
                if (n < NE) {
                    h2 w0 = { m0[2 * q], m0[2 * q + 1] };
                    h2 w1 = { m1[2 * q], m1[2 * q + 1] };
                    h2 w2 = { m2[2 * q], m2[2 * q + 1] };
                    p[n] = A0p * w0 + A1p * w1 + A2p * w2;
                }
            }
        }
        batcher46h2(p);
        float acc0 = 0.f, acc1 = 0.f;
        #pragma unroll
        for (int n = 0; n < NE; n++) {
            float w = w_comb[n * DOC + e];
            acc0 += (float)p[n].x * w;
            acc1 += (float)p[n].y * w;
        }
        dst0[9 + e] = acc0;
        dst1[9 + e] = acc1;
    }
}

// ---------------- stage 2a: projection GEMM ----------------
// P[b][e][c] = sum_d A_graph[d][e] * gvR[b][c][d]
#define KT 32

__global__ __launch_bounds__(256) void proj_gemm(
        const float* __restrict__ gvR, const float* __restrict__ A_graph,
        float* __restrict__ P) {
    __shared__ __align__(16) float As[KT][64];
    __shared__ __align__(16) float Gs[KT][68];
    int b = blockIdx.z;
    int e0 = blockIdx.y * 64;
    int c0 = blockIdx.x * 64;
    int tid = threadIdx.x;
    int tx = tid & 15, ty = tid >> 4;
    float acc[4][4] = {};
    const float* gbase = gvR + (size_t)b * C_TOT * GSTRIDE;

    for (int k0 = 0; k0 < GSTRIDE; k0 += KT) {
        #pragma unroll
        for (int o = 0; o < 8; o++) {
            int idx = o * 256 + tid;
            int kk = idx >> 6, ee = idx & 63;
            int k = k0 + kk, E = e0 + ee;
            As[kk][ee] = (k < DCOMB && E < DGRAPH) ? A_graph[k * DGRAPH + E] : 0.f;
        }
        int kk = tid & 31;
        int cb = tid >> 5;   // 0..7
        #pragma unroll
        for (int o = 0; o < 8; o++) {
            int ccol = o * 8 + cb;
            int C = c0 + ccol;
            Gs[kk][ccol] = (C < C_TOT) ? gbase[(size_t)C * GSTRIDE + k0 + kk] : 0.f;
        }
        __syncthreads();
        #pragma unroll
        for (int k = 0; k < KT; k++) {
            float4 av = *(const float4*)&As[k][ty * 4];
            float4 gq = *(const float4*)&Gs[k][tx * 4];
            float ar[4] = {av.x, av.y, av.z, av.w};
            float gr[4] = {gq.x, gq.y, gq.z, gq.w};
            #pragma unroll
            for (int ii = 0; ii < 4; ii++)
                #pragma unroll
                for (int jj = 0; jj < 4; jj++)
                    acc[ii][jj] += ar[ii] * gr[jj];
        }
        __syncthreads();
    }
    #pragma unroll
    for (int ii = 0; ii < 4; ii++) {
        int e = e0 + ty * 4 + ii;
        int c = c0 + tx * 4;
        if (e < DGRAPH && c < C_TOT) {
            float4 val = make_float4(acc[ii][0], acc[ii][1], acc[ii][2], acc[ii][3]);
            *(float4*)&P[((size_t)b * DGRAPH + e) * C_TOT + c] = val;
        }
    }
}

// ---------------- stage 2b: 4-wave in-register bitonic sort + dot ----------------

#define RPT 16
#define LSTRIDE 17

template<int J, int K>
__device__ __forceinline__ void bpass_in(float v[RPT], int tid) {
    bool upt = ((tid & (K >> 4)) == 0);          // valid for K>=16
    #pragma unroll
    for (int r = 0; r < RPT; r++) {
        int l = r ^ J;
        if (l > r) {
            bool up = (K < 16) ? ((r & K) == 0) : upt;
            float a = v[r], b = v[l];
            float mn = fminf(a, b), mx = fmaxf(a, b);
            v[r] = up ? mn : mx;
            v[l] = up ? mx : mn;
        }
    }
}

template<int JL, int K>
__device__ __forceinline__ void bpass_shfl(float v[RPT], int tid) {
    bool lower = (tid & JL) == 0;
    bool up = (tid & (K >> 4)) == 0;
    bool keep_min = (lower == up);
    #pragma unroll
    for (int r = 0; r < RPT; r++) {
        float pv = __shfl_xor(v[r], JL);
        float mn = fminf(v[r], pv), mx = fmaxf(v[r], pv);
        v[r] = keep_min ? mn : mx;
    }
}

template<int JL, int K>
__device__ __forceinline__ void bpass_lds(float v[RPT], int tid, float* lds) {
    __syncthreads();
    #pragma unroll
    for (int r = 0; r < RPT; r++) lds[tid * LSTRIDE + r] = v[r];
    __syncthreads();
    bool lower = (tid & JL) == 0;
    bool up = (tid & (K >> 4)) == 0;
    bool keep_min = (lower == up);
    int pbase = (tid ^ JL) * LSTRIDE;
    #pragma unroll
    for (int r = 0; r < RPT; r++) {
        float pv = lds[pbase + r];
        float mn = fminf(v[r], pv), mx = fmaxf(v[r], pv);
        v[r] = keep_min ? mn : mx;
    }
}

#define BIN4(K) bpass_in<8,K>(v,tid); bpass_in<4,K>(v,tid); \
                bpass_in<2,K>(v,tid); bpass_in<1,K>(v,tid)

__global__ __launch_bounds__(256) void sort_kernel(
        const float* __restrict__ P, const float* __restrict__ wgT,
        float* __restrict__ out) {
    int blk = blockIdx.x;
    int b = blk / DGRAPH, e = blk % DGRAPH;
    int tid = threadIdx.x;
    __shared__ float lds[256 * LSTRIDE];
    __shared__ float red[4];

    float v[RPT];
    const float* row = P + ((size_t)b * DGRAPH + e) * C_TOT;
    if (tid < 141) {
        const float4* r4 = (const float4*)(row + tid * RPT);
        #pragma unroll
        for (int q = 0; q < 4; q++) {
            float4 tq = r4[q];
            v[q * 4 + 0] = tq.x; v[q * 4 + 1] = tq.y;
            v[q * 4 + 2] = tq.z; v[q * 4 + 3] = tq.w;
        }
    } else {
        #pragma unroll
        for (int r = 0; r < RPT; r++) v[r] = FLT_MAX;
    }

    bpass_in<1,2>(v,tid);
    bpass_in<2,4>(v,tid); bpass_in<1,4>(v,tid);
    bpass_in<4,8>(v,tid); bpass_in<2,8>(v,tid); bpass_in<1,8>(v,tid);
    bpass_in<8,16>(v,tid); bpass_in<4,16>(v,tid); bpass_in<2,16>(v,tid); bpass_in<1,16>(v,tid);
    bpass_shfl<1,32>(v,tid);  BIN4(32);
    bpass_shfl<2,64>(v,tid);  bpass_shfl<1,64>(v,tid);  BIN4(64);
    bpass_shfl<4,128>(v,tid); bpass_shfl<2,128>(v,tid); bpass_shfl<1,128>(v,tid); BIN4(128);
    bpass_shfl<8,256>(v,tid); bpass_shfl<4,256>(v,tid); bpass_shfl<2,256>(v,tid); bpass_shfl<1,256>(v,tid); BIN4(256);
    bpass_shfl<16,512>(v,tid); bpass_shfl<8,512>(v,tid); bpass_shfl<4,512>(v,tid); bpass_shfl<2,512>(v,tid); bpass_shfl<1,512>(v,tid); BIN4(512);
    bpass_shfl<32,1024>(v,tid); bpass_shfl<16,1024>(v,tid); bpass_shfl<8,1024>(v,tid); bpass_shfl<4,1024>(v,tid); bpass_shfl<2,1024>(v,tid); bpass_shfl<1,1024>(v,tid); BIN4(1024);
    bpass_lds<64,2048>(v,tid,lds);
    bpass_shfl<32,2048>(v,tid); bpass_shfl<16,2048>(v,tid); bpass_shfl<8,2048>(v,tid); bpass_shfl<4,2048>(v,tid); bpass_shfl<2,2048>(v,tid); bpass_shfl<1,2048>(v,tid); BIN4(2048);
    bpass_lds<128,4096>(v,tid,lds);
    bpass_lds<64,4096>(v,tid,lds);
    bpass_shfl<32,4096>(v,tid); bpass_shfl<16,4096>(v,tid); bpass_shfl<8,4096>(v,tid); bpass_shfl<4,4096>(v,tid); bpass_shfl<2,4096>(v,tid); bpass_shfl<1,4096>(v,tid); BIN4(4096);

    float acc = 0.f;
    if (tid < 141) {
        const float4* w4 = (const float4*)(wgT + (size_t)e * C_TOT + tid * RPT);
        #pragma unroll
        for (int q = 0; q < 4; q++) {
            float4 tq = w4[q];
            acc += v[q * 4 + 0] * tq.x + v[q * 4 + 1] * tq.y
                 + v[q * 4 + 2] * tq.z + v[q * 4 + 3] * tq.w;
        }
    }
    #pragma unroll
    for (int m = 32; m >= 1; m >>= 1) acc += __shfl_xor(acc, m);
    int wave = tid >> 6, lane = tid & 63;
    if (lane == 0) red[wave] = acc;
    __syncthreads();
    if (tid == 0) out[b * DGRAPH + e] = red[0] + red[1] + red[2] + red[3];
}

// ---------------- launch ----------------

extern "C" void kernel_launch(void* const* d_in, const int* in_sizes, int n_in,
                              void* d_out, int out_size, void* d_ws, size_t ws_size,
                              hipStream_t stream) {
    const float* x       = (const float*)d_in[0];
    const float* A_comb  = (const float*)d_in[1];
    const float* w_comb  = (const float*)d_in[2];
    const float* A_graph = (const float*)d_in[3];
    const float* w_graph = (const float*)d_in[4];
    float* out = (float*)d_out;

    float* ws  = (float*)d_ws;
    float* xc  = ws;                          // 576
    float* wgT = xc + 576;                    // 289*2256 = 651,984
    float* gvR = wgT + 651984;                // 4*2256*288 = 2,598,912
    float* P   = gvR + 2598912;               // 4*289*2256 = 2,607,936

    center_kernel<<<12, 64, 0, stream>>>(x, xc);
    transpose_tiled<<<dim3((C_TOT + 31) / 32, (DGRAPH + 31) / 32), 256, 0, stream>>>(
        w_graph, wgT, C_TOT, DGRAPH);
    pair_kernel<<<BATCH * N_PAIRS, 320, 0, stream>>>(xc, A_comb, w_comb, gvR);
    proj_gemm<<<dim3(36, 5, BATCH), 256, 0, stream>>>(gvR, A_graph, P);
    sort_kernel<<<BATCH * DGRAPH, 256, 0, stream>>>(P, wgT, out);
}

// Round 9
// 144.173 us; speedup vs baseline: 1.7010x; 1.0670x over previous
//
#include <hip/hip_runtime.h>
#include <float.h>

#define N_PTS   48
#define N_PAIRS 1128
#define C_TOT   2256
#define NE      46
#define DOC     277
#define DCOMB   286
#define GSTRIDE 288
#define DGRAPH  289
#define BATCH   4

typedef _Float16 h2 __attribute__((ext_vector_type(2)));
typedef _Float16 h8 __attribute__((ext_vector_type(8)));

// ---------------- prep kernels ----------------

__global__ void center_kernel(const float* __restrict__ x, float* __restrict__ xc) {
    int row = blockIdx.x;              // 12 rows = b*3+d
    int t = threadIdx.x;               // 64 threads
    float v = (t < N_PTS) ? x[row * N_PTS + t] : 0.f;
    float s = v;
    #pragma unroll
    for (int m = 32; m >= 1; m >>= 1) s += __shfl_xor(s, m);
    if (t < N_PTS) xc[row * N_PTS + t] = v - s * (1.0f / N_PTS);
}

// LDS-tiled transpose: out[c*R + r] = in[r*C + c]
__global__ __launch_bounds__(256) void transpose_tiled(const float* __restrict__ in,
                                                       float* __restrict__ out, int R, int C) {
    __shared__ float tile[32][33];
    int r0 = blockIdx.x * 32, c0 = blockIdx.y * 32;
    int tx = threadIdx.x & 31, ty = threadIdx.x >> 5;   // 32 x 8
    #pragma unroll
    for (int yy = 0; yy < 4; yy++) {
        int r = r0 + ty + 8 * yy, c = c0 + tx;
        tile[ty + 8 * yy][tx] = (r < R && c < C) ? in[r * C + c] : 0.f;
    }
    __syncthreads();
    #pragma unroll
    for (int yy = 0; yy < 4; yy++) {
        int c = c0 + ty + 8 * yy, r = r0 + tx;
        if (c < C && r < R) out[(size_t)c * R + r] = tile[tx][ty + 8 * yy];
    }
}

// ---------------- stage 1: per-pair kernel (dual-c packed f16) ----------------

__device__ __forceinline__ void batcher46h2(h2 a[NE]) {
    #pragma unroll
    for (int p = 1; p < 64; p <<= 1) {
        #pragma unroll
        for (int k = p; k >= 1; k >>= 1) {
            #pragma unroll
            for (int j = k % p; j + k < 64; j += 2 * k) {
                #pragma unroll
                for (int i = 0; i < k; i++) {
                    int lo = i + j, hi = i + j + k;
                    if (hi < NE && (lo / (2 * p)) == (hi / (2 * p))) {
                        h2 mn = __builtin_elementwise_min(a[lo], a[hi]);
                        h2 mx = __builtin_elementwise_max(a[lo], a[hi]);
                        a[lo] = mn; a[hi] = mx;
                    }
                }
            }
        }
    }
}

__device__ __forceinline__ void decode_pair(int c, int& fi, int& se, int& pi, int& pj) {
    int cc = c % N_PAIRS;
    bool rev = c >= N_PAIRS;
    int i = 0, rem = cc;
    while (rem >= N_PTS - 1 - i) { rem -= N_PTS - 1 - i; i++; }
    int j = i + 1 + rem;
    pi = i; pj = j;
    fi = rev ? j : i; se = rev ? i : j;
}

__device__ __forceinline__ void pick_row(int k, float x0, float y0, float z0,
                                         float x1, float y1, float z1,
                                         float x2, float y2, float z2,
                                         float& u0, float& u1, float& u2) {
    u0 = (k == 0) ? x0 : (k == 1) ? x1 : x2;
    u1 = (k == 0) ? y0 : (k == 1) ? y1 : y2;
    u2 = (k == 0) ? z0 : (k == 1) ? z1 : z2;
}

// 320 threads per block (5 waves); block handles c0=2k, c1=2k+1 packed in h2.
__global__ __launch_bounds__(320) void pair_kernel(
        const float* __restrict__ xc, const float* __restrict__ A_comb,
        const float* __restrict__ w_comb, float* __restrict__ gvR) {
    int blk = blockIdx.x;
    int b = blk / N_PAIRS, k = blk % N_PAIRS;
    int c0 = 2 * k, c1 = 2 * k + 1;
    int tid = threadIdx.x;

    __shared__ float Xs[3][N_PTS];
    __shared__ h8 MtVp8[3][12];             // rows padded to 48 h2 (96 halves)
    _Float16* MtVh = (_Float16*)MtVp8;      // row d at d*96; entry n at n*2 + half

    if (tid < 3 * N_PTS) ((float*)Xs)[tid] = xc[b * 3 * N_PTS + tid];
    __syncthreads();

    int f0, s0, i0, j0; decode_pair(c0, f0, s0, i0, j0);
    int f1, s1, i1, j1; decode_pair(c1, f1, s1, i1, j1);

    float ax0 = Xs[0][f0], ay0 = Xs[1][f0], az0 = Xs[2][f0];
    float bx0 = Xs[0][s0], by0 = Xs[1][s0], bz0 = Xs[2][s0];
    float cx0 = ay0 * bz0 - az0 * by0;
    float cy0 = az0 * bx0 - ax0 * bz0;
    float cz0 = ax0 * by0 - ay0 * bx0;

    float ax1 = Xs[0][f1], ay1 = Xs[1][f1], az1 = Xs[2][f1];
    float bx1 = Xs[0][s1], by1 = Xs[1][s1], bz1 = Xs[2][s1];
    float cx1 = ay1 * bz1 - az1 * by1;
    float cy1 = az1 * bx1 - ax1 * bz1;
    float cz1 = ax1 * by1 - ay1 * bx1;

    float* dst0 = gvR + ((size_t)b * C_TOT + c0) * GSTRIDE;
    float* dst1 = gvR + ((size_t)b * C_TOT + c1) * GSTRIDE;

    if (tid < NE) {
        int m = tid;
        int a = (m < i0) ? m : m + 1;
        a = (a < j0) ? a : a + 1;
        float v0 = Xs[0][a], v1 = Xs[1][a], v2 = Xs[2][a];
        MtVh[0 * 96 + m * 2] = (_Float16)(ax0 * v0 + ay0 * v1 + az0 * v2);
        MtVh[1 * 96 + m * 2] = (_Float16)(bx0 * v0 + by0 * v1 + bz0 * v2);
        MtVh[2 * 96 + m * 2] = (_Float16)(cx0 * v0 + cy0 * v1 + cz0 * v2);
    } else if (tid >= 64 && tid < 64 + NE) {
        int m = tid - 64;
        int a = (m < i1) ? m : m + 1;
        a = (a < j1) ? a : a + 1;
        float v0 = Xs[0][a], v1 = Xs[1][a], v2 = Xs[2][a];
        MtVh[0 * 96 + m * 2 + 1] = (_Float16)(ax1 * v0 + ay1 * v1 + az1 * v2);
        MtVh[1 * 96 + m * 2 + 1] = (_Float16)(bx1 * v0 + by1 * v1 + bz1 * v2);
        MtVh[2 * 96 + m * 2 + 1] = (_Float16)(cx1 * v0 + cy1 * v1 + cz1 * v2);
    } else if (tid >= 128 && tid < 134) {
        int q = tid - 128;
        int d = q >> 1, n = 46 + (q & 1);   // pad entries n=46,47 of each row
        ((h2*)MtVp8)[d * 48 + n] = (h2){(_Float16)0.f, (_Float16)0.f};
    }

    if (tid >= 160 && tid < 169) {
        int q = tid - 160, kk = q / 3, ll = q % 3;
        float u0, u1, u2, v0, v1, v2;
        pick_row(kk, ax0, ay0, az0, bx0, by0, bz0, cx0, cy0, cz0, u0, u1, u2);
        pick_row(ll, ax0, ay0, az0, bx0, by0, bz0, cx0, cy0, cz0, v0, v1, v2);
        dst0[q] = u0 * v0 + u1 * v1 + u2 * v2;
    }
    if (tid >= 192 && tid < 201) {
        int q = tid - 192, kk = q / 3, ll = q % 3;
        float u0, u1, u2, v0, v1, v2;
        pick_row(kk, ax1, ay1, az1, bx1, by1, bz1, cx1, cy1, cz1, u0, u1, u2);
        pick_row(ll, ax1, ay1, az1, bx1, by1, bz1, cx1, cy1, cz1, v0, v1, v2);
        dst1[q] = u0 * v0 + u1 * v1 + u2 * v2;
    }
    if (tid == 224) { dst0[DCOMB] = 0.f; dst0[DCOMB + 1] = 0.f; }
    if (tid == 225) { dst1[DCOMB] = 0.f; dst1[DCOMB + 1] = 0.f; }
    __syncthreads();

    if (tid < DOC) {
        int e = tid;
        float A0 = A_comb[e], A1 = A_comb[DOC + e], A2 = A_comb[2 * DOC + e];
        h2 A0p = { (_Float16)A0, (_Float16)A0 };
        h2 A1p = { (_Float16)A1, (_Float16)A1 };
        h2 A2p = { (_Float16)A2, (_Float16)A2 };
        h2 p[NE];
        #pragma unroll
        for (int c8 = 0; c8 < 12; c8++) {
            h8 m0 = MtVp8[0][c8];
            h8 m1 = MtVp8[1][c8];
            h8 m2 = MtVp8[2][c8];
            #pragma unroll
            for (int q = 0; q < 4; q++) {
                int n = c8 * 4 + q;
                if (n < NE) {
                    h2 w0 = { m0[2 * q], m0[2 * q + 1] };
                    h2 w1 = { m1[2 * q], m1[2 * q + 1] };
                    h2 w2 = { m2[2 * q], m2[2 * q + 1] };
                    p[n] = A0p * w0 + A1p * w1 + A2p * w2;
                }
            }
        }
        batcher46h2(p);
        float acc0 = 0.f, acc1 = 0.f;
        #pragma unroll
        for (int n = 0; n < NE; n++) {
            float w = w_comb[n * DOC + e];
            acc0 += (float)p[n].x * w;
            acc1 += (float)p[n].y * w;
        }
        dst0[9 + e] = acc0;
        dst1[9 + e] = acc1;
    }
}

// ---------------- stage 2a: projection GEMM ----------------
// P[b][e][c] = sum_d A_graph[d][e] * gvR[b][c][d]
#define KT 32

__global__ __launch_bounds__(256) void proj_gemm(
        const float* __restrict__ gvR, const float* __restrict__ A_graph,
        float* __restrict__ P) {
    __shared__ __align__(16) float As[KT][64];
    __shared__ __align__(16) float Gs[KT][68];
    int b = blockIdx.z;
    int e0 = blockIdx.y * 64;
    int c0 = blockIdx.x * 64;
    int tid = threadIdx.x;
    int tx = tid & 15, ty = tid >> 4;
    float acc[4][4] = {};
    const float* gbase = gvR + (size_t)b * C_TOT * GSTRIDE;

    for (int k0 = 0; k0 < GSTRIDE; k0 += KT) {
        #pragma unroll
        for (int o = 0; o < 8; o++) {
            int idx = o * 256 + tid;
            int kk = idx >> 6, ee = idx & 63;
            int k = k0 + kk, E = e0 + ee;
            As[kk][ee] = (k < DCOMB && E < DGRAPH) ? A_graph[k * DGRAPH + E] : 0.f;
        }
        int kk = tid & 31;
        int cb = tid >> 5;   // 0..7
        #pragma unroll
        for (int o = 0; o < 8; o++) {
            int ccol = o * 8 + cb;
            int C = c0 + ccol;
            Gs[kk][ccol] = (C < C_TOT) ? gbase[(size_t)C * GSTRIDE + k0 + kk] : 0.f;
        }
        __syncthreads();
        #pragma unroll
        for (int k = 0; k < KT; k++) {
            float4 av = *(const float4*)&As[k][ty * 4];
            float4 gq = *(const float4*)&Gs[k][tx * 4];
            float ar[4] = {av.x, av.y, av.z, av.w};
            float gr[4] = {gq.x, gq.y, gq.z, gq.w};
            #pragma unroll
            for (int ii = 0; ii < 4; ii++)
                #pragma unroll
                for (int jj = 0; jj < 4; jj++)
                    acc[ii][jj] += ar[ii] * gr[jj];
        }
        __syncthreads();
    }
    #pragma unroll
    for (int ii = 0; ii < 4; ii++) {
        int e = e0 + ty * 4 + ii;
        int c = c0 + tx * 4;
        if (e < DGRAPH && c < C_TOT) {
            float4 val = make_float4(acc[ii][0], acc[ii][1], acc[ii][2], acc[ii][3]);
            *(float4*)&P[((size_t)b * DGRAPH + e) * C_TOT + c] = val;
        }
    }
}

// ---------------- stage 2b: b-pair packed f16 bitonic sort + dot ----------------
// 256 threads; block handles (b0=2p, b1=2p+1) for one e. Thread owns
// g = tid*16 + r. Packed h2 lanes sort both batches at once (v_pk_min/max).

#define RPT 16
#define LSTRIDE 17

template<int J, int K>
__device__ __forceinline__ void hpass_in(h2 v[RPT], int tid) {
    bool upt = ((tid & (K >> 4)) == 0);          // valid for K>=16
    #pragma unroll
    for (int r = 0; r < RPT; r++) {
        int l = r ^ J;
        if (l > r) {
            bool up = (K < 16) ? ((r & K) == 0) : upt;
            h2 a = v[r], b = v[l];
            h2 mn = __builtin_elementwise_min(a, b);
            h2 mx = __builtin_elementwise_max(a, b);
            v[r] = up ? mn : mx;
            v[l] = up ? mx : mn;
        }
    }
}

template<int JL, int K>
__device__ __forceinline__ void hpass_shfl(h2 v[RPT], int tid) {
    bool lower = (tid & JL) == 0;
    bool up = (tid & (K >> 4)) == 0;
    bool keep_min = (lower == up);
    #pragma unroll
    for (int r = 0; r < RPT; r++) {
        int iv = __builtin_bit_cast(int, v[r]);
        int pvi = __shfl_xor(iv, JL);
        h2 pv = __builtin_bit_cast(h2, pvi);
        h2 mn = __builtin_elementwise_min(v[r], pv);
        h2 mx = __builtin_elementwise_max(v[r], pv);
        v[r] = keep_min ? mn : mx;
    }
}

template<int JL, int K>
__device__ __forceinline__ void hpass_lds(h2 v[RPT], int tid, int* lds) {
    __syncthreads();
    #pragma unroll
    for (int r = 0; r < RPT; r++) lds[tid * LSTRIDE + r] = __builtin_bit_cast(int, v[r]);
    __syncthreads();
    bool lower = (tid & JL) == 0;
    bool up = (tid & (K >> 4)) == 0;
    bool keep_min = (lower == up);
    int pbase = (tid ^ JL) * LSTRIDE;
    #pragma unroll
    for (int r = 0; r < RPT; r++) {
        h2 pv = __builtin_bit_cast(h2, lds[pbase + r]);
        h2 mn = __builtin_elementwise_min(v[r], pv);
        h2 mx = __builtin_elementwise_max(v[r], pv);
        v[r] = keep_min ? mn : mx;
    }
}

#define HBIN4(K) hpass_in<8,K>(v,tid); hpass_in<4,K>(v,tid); \
                 hpass_in<2,K>(v,tid); hpass_in<1,K>(v,tid)

__global__ __launch_bounds__(256) void sort_kernel(
        const float* __restrict__ P, const float* __restrict__ wgT,
        float* __restrict__ out) {
    int blk = blockIdx.x;
    int p = blk / DGRAPH, e = blk % DGRAPH;     // p = 0,1
    int b0 = 2 * p, b1 = 2 * p + 1;
    int tid = threadIdx.x;
    __shared__ int lds[256 * LSTRIDE];
    __shared__ float red0[4], red1[4];

    h2 v[RPT];
    const float* row0 = P + ((size_t)b0 * DGRAPH + e) * C_TOT;
    const float* row1 = P + ((size_t)b1 * DGRAPH + e) * C_TOT;
    if (tid < 141) {
        const float4* r40 = (const float4*)(row0 + tid * RPT);
        const float4* r41 = (const float4*)(row1 + tid * RPT);
        #pragma unroll
        for (int q = 0; q < 4; q++) {
            float4 t0 = r40[q];
            float4 t1 = r41[q];
            v[q * 4 + 0] = (h2){(_Float16)t0.x, (_Float16)t1.x};
            v[q * 4 + 1] = (h2){(_Float16)t0.y, (_Float16)t1.y};
            v[q * 4 + 2] = (h2){(_Float16)t0.z, (_Float16)t1.z};
            v[q * 4 + 3] = (h2){(_Float16)t0.w, (_Float16)t1.w};
        }
    } else {
        #pragma unroll
        for (int r = 0; r < RPT; r++)
            v[r] = (h2){(_Float16)65504.f, (_Float16)65504.f};
    }

    hpass_in<1,2>(v,tid);
    hpass_in<2,4>(v,tid); hpass_in<1,4>(v,tid);
    hpass_in<4,8>(v,tid); hpass_in<2,8>(v,tid); hpass_in<1,8>(v,tid);
    hpass_in<8,16>(v,tid); hpass_in<4,16>(v,tid); hpass_in<2,16>(v,tid); hpass_in<1,16>(v,tid);
    hpass_shfl<1,32>(v,tid);  HBIN4(32);
    hpass_shfl<2,64>(v,tid);  hpass_shfl<1,64>(v,tid);  HBIN4(64);
    hpass_shfl<4,128>(v,tid); hpass_shfl<2,128>(v,tid); hpass_shfl<1,128>(v,tid); HBIN4(128);
    hpass_shfl<8,256>(v,tid); hpass_shfl<4,256>(v,tid); hpass_shfl<2,256>(v,tid); hpass_shfl<1,256>(v,tid); HBIN4(256);
    hpass_shfl<16,512>(v,tid); hpass_shfl<8,512>(v,tid); hpass_shfl<4,512>(v,tid); hpass_shfl<2,512>(v,tid); hpass_shfl<1,512>(v,tid); HBIN4(512);
    hpass_shfl<32,1024>(v,tid); hpass_shfl<16,1024>(v,tid); hpass_shfl<8,1024>(v,tid); hpass_shfl<4,1024>(v,tid); hpass_shfl<2,1024>(v,tid); hpass_shfl<1,1024>(v,tid); HBIN4(1024);
    hpass_lds<64,2048>(v,tid,lds);
    hpass_shfl<32,2048>(v,tid); hpass_shfl<16,2048>(v,tid); hpass_shfl<8,2048>(v,tid); hpass_shfl<4,2048>(v,tid); hpass_shfl<2,2048>(v,tid); hpass_shfl<1,2048>(v,tid); HBIN4(2048);
    hpass_lds<128,4096>(v,tid,lds);
    hpass_lds<64,4096>(v,tid,lds);
    hpass_shfl<32,4096>(v,tid); hpass_shfl<16,4096>(v,tid); hpass_shfl<8,4096>(v,tid); hpass_shfl<4,4096>(v,tid); hpass_shfl<2,4096>(v,tid); hpass_shfl<1,4096>(v,tid); HBIN4(4096);

    float acc0 = 0.f, acc1 = 0.f;
    if (tid < 141) {
        const float4* w4 = (const float4*)(wgT + (size_t)e * C_TOT + tid * RPT);
        #pragma unroll
        for (int q = 0; q < 4; q++) {
            float4 tq = w4[q];
            float wr[4] = {tq.x, tq.y, tq.z, tq.w};
            #pragma unroll
            for (int u = 0; u < 4; u++) {
                acc0 += (float)v[q * 4 + u].x * wr[u];
                acc1 += (float)v[q * 4 + u].y * wr[u];
            }
        }
    }
    #pragma unroll
    for (int m = 32; m >= 1; m >>= 1) {
        acc0 += __shfl_xor(acc0, m);
        acc1 += __shfl_xor(acc1, m);
    }
    int wave = tid >> 6, lane = tid & 63;
    if (lane == 0) { red0[wave] = acc0; red1[wave] = acc1; }
    __syncthreads();
    if (tid == 0) {
        out[b0 * DGRAPH + e] = red0[0] + red0[1] + red0[2] + red0[3];
        out[b1 * DGRAPH + e] = red1[0] + red1[1] + red1[2] + red1[3];
    }
}

// ---------------- launch ----------------

extern "C" void kernel_launch(void* const* d_in, const int* in_sizes, int n_in,
                              void* d_out, int out_size, void* d_ws, size_t ws_size,
                              hipStream_t stream) {
    const float* x       = (const float*)d_in[0];
    const float* A_comb  = (const float*)d_in[1];
    const float* w_comb  = (const float*)d_in[2];
    const float* A_graph = (const float*)d_in[3];
    const float* w_graph = (const float*)d_in[4];
    float* out = (float*)d_out;

    float* ws  = (float*)d_ws;
    float* xc  = ws;                          // 576
    float* wgT = xc + 576;                    // 289*2256 = 651,984
    float* gvR = wgT + 651984;                // 4*2256*288 = 2,598,912
    float* P   = gvR + 2598912;               // 4*289*2256 = 2,607,936

    center_kernel<<<12, 64, 0, stream>>>(x, xc);
    transpose_tiled<<<dim3((C_TOT + 31) / 32, (DGRAPH + 31) / 32), 256, 0, stream>>>(
        w_graph, wgT, C_TOT, DGRAPH);
    pair_kernel<<<BATCH * N_PAIRS, 320, 0, stream>>>(xc, A_comb, w_comb, gvR);
    proj_gemm<<<dim3(36, 5, BATCH), 256, 0, stream>>>(gvR, A_graph, P);
    sort_kernel<<<2 * DGRAPH, 256, 0, stream>>>(P, wgT, out);
}